// Round 4
// baseline (3241.334 us; speedup 1.0000x reference)
//
#include <hip/hip_runtime.h>
#include <hip/hip_bf16.h>

// Problem constants
#define B_   64
#define N_   200
#define S_   201
#define E_   128
#define H_   8
#define D_   16
#define HD_  128
#define FF_  512
#define L_   6
#define TWOH_ 16
#define NCH_ 2              // n's per attn block
#define NCHB_ 101           // ceil(S_/NCH_)
#define PADM_ 208           // padded m stride for PL

// ---------------- initial embedding ----------------
__global__ void embed_kernel(const float* __restrict__ depot, const float* __restrict__ node,
                             const float* __restrict__ Wd, const float* __restrict__ bd,
                             const float* __restrict__ Wn, const float* __restrict__ bn,
                             float* __restrict__ X) {
  int idx = blockIdx.x * blockDim.x + threadIdx.x;
  if (idx >= B_ * S_ * E_) return;
  int e  = idx & (E_ - 1);
  int bs = idx >> 7;
  int s  = bs % S_;
  int b  = bs / S_;
  float acc;
  if (s == 0) {
    acc = bd[e];
    #pragma unroll
    for (int i = 0; i < 3; ++i) acc += depot[b * 3 + i] * Wd[i * E_ + e];
  } else {
    acc = bn[e];
    const float* nd = node + ((size_t)b * N_ + (s - 1)) * 4;
    #pragma unroll
    for (int i = 0; i < 4; ++i) acc += nd[i] * Wn[i * E_ + e];
  }
  X[idx] = acc;
}

// ---------------- generic tiled GEMM (f32) ----------------
__global__ __launch_bounds__(256) void gemm_kernel(
    const float* __restrict__ A, const float* __restrict__ W,
    const float* __restrict__ bias, const float* __restrict__ res,
    float* __restrict__ C, int M, int N, int K, int relu) {
  __shared__ float As[64][33];
  __shared__ float Ws[32][64];
  int tid = threadIdx.x;
  int m0 = blockIdx.x * 64;
  int n0 = blockIdx.y * 64;
  int tx = tid & 15, ty = tid >> 4;
  float acc[4][4] = {};
  for (int k0 = 0; k0 < K; k0 += 32) {
    {
      int p = tid * 8;
      int r = p >> 5, c = p & 31;
      const float* src = A + (size_t)(m0 + r) * K + k0 + c;
      #pragma unroll
      for (int i = 0; i < 8; ++i) As[r][c + i] = src[i];
    }
    {
      int p = tid * 8;
      int r = p >> 6, c = p & 63;
      const float* src = W + (size_t)(k0 + r) * N + n0 + c;
      #pragma unroll
      for (int i = 0; i < 8; ++i) Ws[r][c + i] = src[i];
    }
    __syncthreads();
    #pragma unroll
    for (int kk = 0; kk < 32; ++kk) {
      float a[4], w[4];
      #pragma unroll
      for (int i = 0; i < 4; ++i) a[i] = As[ty * 4 + i][kk];
      #pragma unroll
      for (int j = 0; j < 4; ++j) w[j] = Ws[kk][tx * 4 + j];
      #pragma unroll
      for (int i = 0; i < 4; ++i)
        #pragma unroll
        for (int j = 0; j < 4; ++j) acc[i][j] += a[i] * w[j];
    }
    __syncthreads();
  }
  #pragma unroll
  for (int i = 0; i < 4; ++i) {
    int m = m0 + ty * 4 + i;
    #pragma unroll
    for (int j = 0; j < 4; ++j) {
      int n = n0 + tx * 4 + j;
      float v = acc[i][j];
      if (bias) v += bias[n];
      if (res)  v += res[(size_t)m * N + n];
      if (relu) v = v > 0.f ? v : 0.f;
      C[(size_t)m * N + n] = v;
    }
  }
}

// ---------------- attention scores ----------------
__global__ __launch_bounds__(256) void score_kernel(const float* __restrict__ Q,
                                                    const float* __restrict__ Kmat,
                                                    float* __restrict__ SC) {
  int bh = blockIdx.x;
  int h = bh % H_, b = bh / H_;
  __shared__ float qs[S_][D_ + 1];
  __shared__ float ks[S_][D_ + 1];
  int tid = threadIdx.x;
  for (int p = tid; p < S_ * D_; p += 256) {
    int r = p >> 4, d = p & 15;
    size_t g = ((size_t)(b * S_ + r)) * HD_ + h * D_ + d;
    qs[r][d] = Q[g];
    ks[r][d] = Kmat[g];
  }
  __syncthreads();
  float* out = SC + ((size_t)(b * H_ + h)) * S_ * S_;
  for (int p = tid; p < S_ * S_; p += 256) {
    int n = p / S_, m = p - n * S_;
    float acc = 0.f;
    #pragma unroll
    for (int d = 0; d < D_; ++d) acc += qs[n][d] * ks[m][d];
    out[(size_t)n * S_ + m] = acc;
  }
}

// ---------------- fused: edge-MLP + softmax + PV, 2 n's per block ----------------
__global__ __launch_bounds__(256, 4) void attn_kernel(
    const float* __restrict__ SC, const float* __restrict__ RA,
    const float* __restrict__ A1w, const float* __restrict__ A1b,
    const float* __restrict__ A2w, const float* __restrict__ A2b,
    const float* __restrict__ V, float* __restrict__ O) {
  int blk = blockIdx.x;
  int b  = blk / NCHB_;
  int n0 = (blk % NCHB_) * NCH_;
  int NV = min(NCH_, S_ - n0);
  __shared__ float PL[NCH_][H_][PADM_];
  __shared__ float partial[2][NCH_][H_][D_];
  __shared__ float inv[NCH_][H_];
  int tid = threadIdx.x;

  // ---- phase 1: edge MLP, 2 edges per thread, inputs straight from global ----
  {
    float cc[2][16];
    int   mm[2], nnv[2];
    bool  val[2];
    #pragma unroll
    for (int k = 0; k < 2; ++k) {
      int e = tid + 256 * k;
      val[k] = (e < NV * S_);
      int nn = (e >= S_) ? 1 : 0;
      int m  = e - nn * S_;
      nnv[k] = nn; mm[k] = m;
      #pragma unroll
      for (int h = 0; h < H_; ++h) {
        size_t r = (((size_t)b * H_ + h) * S_ + (n0 + nn)) * S_ + m;
        cc[k][h]      = val[k] ? SC[r] : 0.f;
        cc[k][H_ + h] = val[k] ? RA[r] : 0.f;
      }
    }
    float h1[2][16];
    #pragma unroll
    for (int j = 0; j < 16; ++j) { float bj = A1b[j]; h1[0][j] = bj; h1[1][j] = bj; }
    #pragma unroll
    for (int i = 0; i < 16; ++i) {
      #pragma unroll
      for (int j = 0; j < 16; ++j) {
        float w = A1w[i * 16 + j];          // uniform -> s_load, SGPR operand
        h1[0][j] += cc[0][i] * w;
        h1[1][j] += cc[1][i] * w;
      }
    }
    float agg[2][8];
    #pragma unroll
    for (int h = 0; h < 8; ++h) { float bh = A2b[h]; agg[0][h] = bh; agg[1][h] = bh; }
    #pragma unroll
    for (int j = 0; j < 16; ++j) {
      float r0 = fmaxf(h1[0][j], 0.f), r1 = fmaxf(h1[1][j], 0.f);
      #pragma unroll
      for (int h = 0; h < 8; ++h) {
        float w = A2w[j * 8 + h];
        agg[0][h] += r0 * w;
        agg[1][h] += r1 * w;
      }
    }
    #pragma unroll
    for (int k = 0; k < 2; ++k)
      if (val[k]) {
        #pragma unroll
        for (int h = 0; h < 8; ++h) PL[nnv[k]][h][mm[k]] = agg[k][h];
      }
  }
  __syncthreads();

  // ---- phase 2: softmax over m, 16 lanes per (nn,h) group ----
  {
    int g = tid >> 4, lane = tid & 15;
    int nn = g >> 3, h = g & 7;
    if (nn < NV) {
      float mx = -1e30f;
      for (int m = lane; m < S_; m += 16) mx = fmaxf(mx, PL[nn][h][m]);
      #pragma unroll
      for (int off = 1; off < 16; off <<= 1) mx = fmaxf(mx, __shfl_xor(mx, off));
      float sum = 0.f;
      for (int m = lane; m < S_; m += 16) {
        float e = __expf(PL[nn][h][m] - mx);
        PL[nn][h][m] = e;
        sum += e;
      }
      #pragma unroll
      for (int off = 1; off < 16; off <<= 1) sum += __shfl_xor(sum, off);
      if (lane == 0) inv[nn][h] = 1.f / sum;
    }
  }
  __syncthreads();

  // ---- phase 3: PV, all 256 threads: (half of m) x (h,d); 2 n-accumulators per load ----
  {
    int half = tid >> 7, h = (tid >> 4) & 7, d = tid & 15;
    float a0 = 0.f, a1 = 0.f;
    const float* vp = V + (size_t)b * S_ * HD_ + h * D_ + d;
    for (int m = half; m < S_; m += 2) {
      float vv = vp[(size_t)m * HD_];
      a0 += PL[0][h][m] * vv;
      a1 += PL[1][h][m] * vv;
    }
    partial[half][0][h][d] = a0;
    partial[half][1][h][d] = a1;
  }
  __syncthreads();
  if (tid < 128) {
    int h = tid >> 4, d = tid & 15;
    #pragma unroll
    for (int nn = 0; nn < NCH_; ++nn)
      if (nn < NV) {
        float s = (partial[0][nn][h][d] + partial[1][nn][h][d]) * inv[nn][h];
        O[((size_t)b * S_ + (n0 + nn)) * HD_ + h * D_ + d] = s;
      }
  }
}

// ---------------- instance norm over sequence axis ----------------
__global__ __launch_bounds__(512) void inorm_kernel(const float* __restrict__ Y,
                                                    const float* __restrict__ w,
                                                    const float* __restrict__ bb,
                                                    float* __restrict__ X) {
  int b = blockIdx.x;
  int tid = threadIdx.x;
  int e = tid & 127, sg = tid >> 7;
  __shared__ float ps[4][128], pss[4][128];
  const float* base = Y + (size_t)b * S_ * E_;
  float s = 0.f, ss = 0.f;
  for (int i = sg; i < S_; i += 4) {
    float v = base[(size_t)i * E_ + e];
    s += v; ss += v * v;
  }
  ps[sg][e] = s; pss[sg][e] = ss;
  __syncthreads();
  if (sg == 0) {
    s  = ps[0][e] + ps[1][e] + ps[2][e] + ps[3][e];
    ss = pss[0][e] + pss[1][e] + pss[2][e] + pss[3][e];
    float mean = s / S_;
    float var  = fmaxf(ss / S_ - mean * mean, 0.f);
    float scale = rsqrtf(var + 1e-5f) * w[e];
    ps[0][e]  = scale;
    pss[0][e] = bb[e] - mean * scale;
  }
  __syncthreads();
  float scale = ps[0][e], shift = pss[0][e];
  float* dst = X + (size_t)b * S_ * E_;
  for (int i = sg; i < S_; i += 4) {
    size_t idx = (size_t)i * E_ + e;
    dst[idx] = base[idx] * scale + shift;
  }
}

extern "C" void kernel_launch(void* const* d_in, const int* in_sizes, int n_in,
                              void* d_out, int out_size, void* d_ws, size_t ws_size,
                              hipStream_t stream) {
  const float* depot = (const float*)d_in[0];
  const float* node  = (const float*)d_in[1];
  const float* RA    = (const float*)d_in[2];
  const float* Wd    = (const float*)d_in[3];
  const float* bd    = (const float*)d_in[4];
  const float* Wn    = (const float*)d_in[5];
  const float* bn    = (const float*)d_in[6];
  const float* Wq    = (const float*)d_in[7];
  const float* Wk    = (const float*)d_in[8];
  const float* Wv    = (const float*)d_in[9];
  const float* Wo    = (const float*)d_in[10];
  const float* bo    = (const float*)d_in[11];
  const float* A1w   = (const float*)d_in[12];
  const float* A1b   = (const float*)d_in[13];
  const float* A2w   = (const float*)d_in[14];
  const float* A2b   = (const float*)d_in[15];
  const float* n1w   = (const float*)d_in[16];
  const float* n1b   = (const float*)d_in[17];
  const float* n2w   = (const float*)d_in[18];
  const float* n2b   = (const float*)d_in[19];
  const float* F1w   = (const float*)d_in[20];
  const float* F1b   = (const float*)d_in[21];
  const float* F2w   = (const float*)d_in[22];
  const float* F2b   = (const float*)d_in[23];

  const size_t XSZ  = (size_t)B_ * S_ * E_;
  const size_t SCSZ = (size_t)B_ * H_ * S_ * S_;
  float* ws = (float*)d_ws;
  float* X   = ws;
  float* Q   = X  + XSZ;
  float* Kb  = Q  + XSZ;
  float* V   = Kb + XSZ;
  float* O   = V  + XSZ;
  float* SC  = O  + XSZ;
  float* TMP = SC;            // aliases SC (SC consumed before TMP written)
  float* HID = SC + XSZ;      // aliases SC tail

  const int M = B_ * S_;

  auto gemm = [&](const float* A, const float* W, const float* bias,
                  const float* res, float* C, int Nn, int K, int relu) {
    dim3 grid(M / 64, Nn / 64);
    gemm_kernel<<<grid, 256, 0, stream>>>(A, W, bias, res, C, M, Nn, K, relu);
  };

  embed_kernel<<<(B_ * S_ * E_ + 255) / 256, 256, 0, stream>>>(depot, node, Wd, bd, Wn, bn, X);

  for (int l = 0; l < L_; ++l) {
    gemm(X, Wq + (size_t)l * E_ * HD_, nullptr, nullptr, Q,  HD_, E_, 0);
    gemm(X, Wk + (size_t)l * E_ * HD_, nullptr, nullptr, Kb, HD_, E_, 0);
    gemm(X, Wv + (size_t)l * E_ * HD_, nullptr, nullptr, V,  HD_, E_, 0);
    score_kernel<<<B_ * H_, 256, 0, stream>>>(Q, Kb, SC);
    attn_kernel<<<B_ * NCHB_, 256, 0, stream>>>(SC, RA,
        A1w + (size_t)l * TWOH_ * TWOH_, A1b + (size_t)l * TWOH_,
        A2w + (size_t)l * TWOH_ * H_,    A2b + (size_t)l * H_, V, O);
    gemm(O, Wo + (size_t)l * HD_ * E_, bo + (size_t)l * E_, X, TMP, E_, HD_, 0);
    inorm_kernel<<<B_, 512, 0, stream>>>(TMP, n1w + (size_t)l * E_, n1b + (size_t)l * E_, X);
    gemm(X, F1w + (size_t)l * E_ * FF_, F1b + (size_t)l * FF_, nullptr, HID, FF_, E_, 1);
    gemm(HID, F2w + (size_t)l * FF_ * E_, F2b + (size_t)l * E_, X, TMP, E_, FF_, 0);
    float* dst = (l == L_ - 1) ? (float*)d_out : X;
    inorm_kernel<<<B_, 512, 0, stream>>>(TMP, n2w + (size_t)l * E_, n2b + (size_t)l * E_, dst);
  }
}